// Round 17
// baseline (120.703 us; speedup 1.0000x reference)
//
#include <hip/hip_runtime.h>
#include <math.h>

#define DDIM 256
#define HDIM 64
#define NTOK 1024
#define BDIM 256
#define NCH  64      // chunks per batch (NTOK/16, one chunk per wave)

typedef __attribute__((ext_vector_type(8))) short short8;
typedef __attribute__((ext_vector_type(4))) float f32x4;

__device__ __forceinline__ ushort f2bf(float f) {   // RNE f32 -> bf16 bits
    uint u = __float_as_uint(f);
    return (ushort)((u + 0x7FFF + ((u >> 16) & 1)) >> 16);
}
__device__ __forceinline__ float bf2f(ushort b) {
    return __uint_as_float(((uint)b) << 16);
}

// Abramowitz-Stegun 7.1.26 erf, |err| <= 1.5e-7.
__device__ __forceinline__ float erf_fast(float x) {
    float ax = fabsf(x);
    float t  = __builtin_amdgcn_rcpf(fmaf(0.3275911f, ax, 1.0f));
    float e  = __expf(-ax * ax);
    float p  = t * fmaf(t, fmaf(t, fmaf(t, fmaf(t, 1.061405429f, -1.453152027f),
                                        1.421413741f), -0.284496736f), 0.254829592f);
    float r  = fmaf(-p, e, 1.0f);
    return copysignf(r, x);
}

// ---------------- k_pre: c12 + split-bf16 pack of G = gamma ⊙ W1 in B-frag order,
// separate hi/lo planes (validated R12/R15: coalesced 16B-stride fragment loads).
__global__ void k_pre(const float* __restrict__ gamma, const float* __restrict__ beta,
                      const float* __restrict__ W1, const float* __restrict__ b1,
                      float* __restrict__ c12, ushort* __restrict__ ghi,
                      ushort* __restrict__ glo) {
    int tid = threadIdx.x;
    if (blockIdx.x == 0 && tid < HDIM) {
        float s1 = 0.f, s2 = 0.f;
        for (int d = 0; d < DDIM; ++d) {
            float w = W1[d * HDIM + tid];
            s1 = fmaf(gamma[d], w, s1);
            s2 = fmaf(beta[d],  w, s2);
        }
        c12[tid]        = s1;
        c12[HDIM + tid] = s2 + b1[tid];
    }
    int e = blockIdx.x * 256 + tid;            // 64 blocks x 256 = 16384 entries
    int j    = e & 7;
    int lane = (e >> 3) & 63;
    int nt   = (e >> 9) & 3;
    int kt   = e >> 11;
    int k = kt * 32 + (lane >> 4) * 8 + j;
    int n = nt * 16 + (lane & 15);
    float g = gamma[k] * W1[k * HDIM + n];
    ushort hi = f2bf(g);
    ushort lo = f2bf(g - bf2f(hi));
    ghi[e] = hi;
    glo[e] = lo;
}

// ---------------- k_fused v7: R12 phase-1 machinery, LDS = Xh ONLY (32KB exact ->
// 5 blocks/CU), ZERO barriers. slog replaced by __shfl broadcasts (butterfly
// epilogue leaves the reduced logit in every lane of the m-group); Sw replaced
// by per-wave Sc chunks (NCH=64, R11-validated combine). Wave-private Xh slices.
__global__ __launch_bounds__(256, 5) void k_fused(
    const float* __restrict__ x, const float* __restrict__ c12,
    const ushort* __restrict__ ghi, const ushort* __restrict__ glo,
    const float* __restrict__ W2, float* __restrict__ logits,
    float* __restrict__ Sc, float2* __restrict__ ml) {
    __shared__ ushort Xh[64][256];   // 32768B exactly: bf16-hi, wave-private slices

    int tid = threadIdx.x, w = tid >> 6, lane = tid & 63;
    int m = lane & 15, kg = lane >> 4;
    size_t wtok = (size_t)blockIdx.x * 64 + (size_t)w * 16;   // wave's 16 tokens

    const float4* rp  = reinterpret_cast<const float4*>(x + (wtok + m) * DDIM + kg * 8);
    const short8* gph = reinterpret_cast<const short8*>(ghi);
    const short8* gpl = reinterpret_cast<const short8*>(glo);
    char* xh_w = reinterpret_cast<char*>(Xh) + (w * 16 + m) * 512;
    uint  swz  = ((uint)(m & 7)) << 4;

    f32x4 acc[4];
    #pragma unroll
    for (int nt = 0; nt < 4; ++nt) acc[nt] = (f32x4){0.f, 0.f, 0.f, 0.f};

    float s1 = 0.f, s2 = 0.f;

    #pragma unroll
    for (int kt = 0; kt < 8; ++kt) {
        float4 xa = rp[kt * 8];        // k = kt*32 + kg*8 + {0..3}
        float4 xb = rp[kt * 8 + 1];    // k = kt*32 + kg*8 + {4..7}

        s1 += ((xa.x + xa.y) + (xa.z + xa.w)) + ((xb.x + xb.y) + (xb.z + xb.w));
        s2 = fmaf(xa.x, xa.x, s2); s2 = fmaf(xa.y, xa.y, s2);
        s2 = fmaf(xa.z, xa.z, s2); s2 = fmaf(xa.w, xa.w, s2);
        s2 = fmaf(xb.x, xb.x, s2); s2 = fmaf(xb.y, xb.y, s2);
        s2 = fmaf(xb.z, xb.z, s2); s2 = fmaf(xb.w, xb.w, s2);

        uint u0 = __float_as_uint(xa.x), u1 = __float_as_uint(xa.y);
        uint u2 = __float_as_uint(xa.z), u3 = __float_as_uint(xa.w);
        uint u4 = __float_as_uint(xb.x), u5 = __float_as_uint(xb.y);
        uint u6 = __float_as_uint(xb.z), u7 = __float_as_uint(xb.w);

        // RNE hi: t = u + 0x7FFF + round_bit; hi<<16 = t & 0xFFFF0000.
        uint t0 = u0 + 0x7FFFu + ((u0 >> 16) & 1u);
        uint t1 = u1 + 0x7FFFu + ((u1 >> 16) & 1u);
        uint t2 = u2 + 0x7FFFu + ((u2 >> 16) & 1u);
        uint t3 = u3 + 0x7FFFu + ((u3 >> 16) & 1u);
        uint t4 = u4 + 0x7FFFu + ((u4 >> 16) & 1u);
        uint t5 = u5 + 0x7FFFu + ((u5 >> 16) & 1u);
        uint t6 = u6 + 0x7FFFu + ((u6 >> 16) & 1u);
        uint t7 = u7 + 0x7FFFu + ((u7 >> 16) & 1u);

        union { uint4 u; short8 s; } Ah, Al;
        Ah.u.x = (t0 >> 16) | (t1 & 0xFFFF0000u);
        Ah.u.y = (t2 >> 16) | (t3 & 0xFFFF0000u);
        Ah.u.z = (t4 >> 16) | (t5 & 0xFFFF0000u);
        Ah.u.w = (t6 >> 16) | (t7 & 0xFFFF0000u);

        // exact residual vs RNE hi, then RTZ to bf16.
        float l0 = xa.x - __uint_as_float(t0 & 0xFFFF0000u);
        float l1 = xa.y - __uint_as_float(t1 & 0xFFFF0000u);
        float l2 = xa.z - __uint_as_float(t2 & 0xFFFF0000u);
        float l3 = xa.w - __uint_as_float(t3 & 0xFFFF0000u);
        float l4 = xb.x - __uint_as_float(t4 & 0xFFFF0000u);
        float l5 = xb.y - __uint_as_float(t5 & 0xFFFF0000u);
        float l6 = xb.z - __uint_as_float(t6 & 0xFFFF0000u);
        float l7 = xb.w - __uint_as_float(t7 & 0xFFFF0000u);
        Al.u.x = (__float_as_uint(l0) >> 16) | (__float_as_uint(l1) & 0xFFFF0000u);
        Al.u.y = (__float_as_uint(l2) >> 16) | (__float_as_uint(l3) & 0xFFFF0000u);
        Al.u.z = (__float_as_uint(l4) >> 16) | (__float_as_uint(l5) & 0xFFFF0000u);
        Al.u.w = (__float_as_uint(l6) >> 16) | (__float_as_uint(l7) & 0xFFFF0000u);

        // Stash hi tile for phase 2 (swizzled; wave-private slice, no barrier).
        *reinterpret_cast<uint4*>(xh_w + (((uint)(kt * 64 + kg * 16)) ^ swz)) = Ah.u;

        #pragma unroll
        for (int nt = 0; nt < 4; ++nt) {
            int frag = (kt * 4 + nt) * 64 + lane;
            short8 bh = gph[frag];     // lane-stride 16B: coalesced, 8 lines/instr
            short8 bl = gpl[frag];
            acc[nt] = __builtin_amdgcn_mfma_f32_16x16x32_bf16(Ah.s, bh, acc[nt], 0, 0, 0);
            acc[nt] = __builtin_amdgcn_mfma_f32_16x16x32_bf16(Al.s, bh, acc[nt], 0, 0, 0);
            acc[nt] = __builtin_amdgcn_mfma_f32_16x16x32_bf16(Ah.s, bl, acc[nt], 0, 0, 0);
        }
    }

    // Row stats: union over the 4 kg-groups = full row; reduce across kg.
    s1 += __shfl_xor(s1, 16); s1 += __shfl_xor(s1, 32);
    s2 += __shfl_xor(s2, 16); s2 += __shfl_xor(s2, 32);
    float mu  = s1 * (1.f / DDIM);
    float var = fmaf(-mu, mu, s2 * (1.f / DDIM));
    float sv  = rsqrtf(var + 1e-5f);

    // Epilogue: LN fixup + fast-erf GELU + W2 dot. The xor-butterfly leaves the
    // reduced logit in ALL 16 lanes of the m-group -> keep v[4] in registers.
    float c1v[4], c2v[4], w2v[4];
    #pragma unroll
    for (int nt = 0; nt < 4; ++nt) {
        c1v[nt] = c12[nt * 16 + m];
        c2v[nt] = c12[HDIM + nt * 16 + m];
        w2v[nt] = W2[nt * 16 + m];
    }
    float v[4];
    #pragma unroll
    for (int r = 0; r < 4; ++r) {
        int row = kg * 4 + r;
        float mur = __shfl(mu, row);
        float svr = __shfl(sv, row);
        float t = 0.f;
        #pragma unroll
        for (int nt = 0; nt < 4; ++nt) {
            float pre = fmaf(svr, fmaf(-mur, c1v[nt], acc[r == 0 ? nt : nt][r]), c2v[nt]);
            float g   = 0.5f * pre * (1.f + erf_fast(pre * 0.70710678118654752f));
            t = fmaf(g, w2v[nt], t);
        }
        t += __shfl_xor(t, 1); t += __shfl_xor(t, 2);
        t += __shfl_xor(t, 4); t += __shfl_xor(t, 8);
        v[r] = t;                                  // uniform across the m-group
        if (m == 0) logits[wtok + row] = t;
    }

    // ---- Phase 2 (no barrier): per-wave softmax via shfl + weighted sum from Xh.
    float lg[16];
    #pragma unroll
    for (int row = 0; row < 16; ++row)
        lg[row] = __shfl(v[row & 3], (row >> 2) << 4);   // source lane kg'*16
    float mc = lg[0];
    #pragma unroll
    for (int row = 1; row < 16; ++row) mc = fmaxf(mc, lg[row]);

    float4 a4 = {0.f, 0.f, 0.f, 0.f};
    float lw = 0.f;
    const char* xh_r = reinterpret_cast<const char*>(Xh) + (size_t)w * 16 * 512;
    uint cb0 = 8u * (uint)lane;                   // lane owns cols 4l..4l+3
    #pragma unroll
    for (int r = 0; r < 16; ++r) {
        float p = __expf(lg[r] - mc);             // uniform across lanes
        lw += p;
        uint2 hb = *reinterpret_cast<const uint2*>(
            xh_r + r * 512 + (cb0 ^ (((uint)(r & 7)) << 4)));
        a4.x = fmaf(p, __uint_as_float(hb.x << 16),         a4.x);
        a4.y = fmaf(p, __uint_as_float(hb.x & 0xFFFF0000u), a4.y);
        a4.z = fmaf(p, __uint_as_float(hb.y << 16),         a4.z);
        a4.w = fmaf(p, __uint_as_float(hb.y & 0xFFFF0000u), a4.w);
    }
    size_t chunk = (size_t)blockIdx.x * 4 + w;    // = b*64 + chunk-in-batch
    reinterpret_cast<float4*>(Sc + chunk * DDIM)[lane] = a4;
    if (lane == 0) ml[chunk] = make_float2(mc, lw);   // lw uniform: no reduce
}

// ---------------- k_combine: per batch, merge 64 chunks -> summary + weights.
// (R11-validated correctness.)
__global__ __launch_bounds__(256) void k_combine(
    const float* __restrict__ Sc, const float2* __restrict__ ml,
    float* __restrict__ summary, float* __restrict__ wts) {
    __shared__ float exs[NCH];
    __shared__ float sM, sInv;
    int b = blockIdx.x, tid = threadIdx.x;

    if (tid < 64) {                                // wave 0: M, denom, ex[c]
        float2 v = ml[b * NCH + tid];
        float M = v.x;
        #pragma unroll
        for (int off = 1; off < 64; off <<= 1) M = fmaxf(M, __shfl_xor(M, off));
        float e   = __expf(v.x - M);
        float den = e * v.y;
        #pragma unroll
        for (int off = 1; off < 64; off <<= 1) den += __shfl_xor(den, off);
        exs[tid] = e;
        if (tid == 0) { sM = M; sInv = 1.f / den; }
    }
    __syncthreads();
    float M = sM, inv = sInv;

    float s = 0.f;
    #pragma unroll 8
    for (int c = 0; c < NCH; ++c)
        s = fmaf(exs[c], Sc[((size_t)b * NCH + c) * DDIM + tid], s);
    summary[(size_t)b * DDIM + tid] = s * inv;

    // weights: 4 tokens per thread, in-place over staged logits.
    float4* wp = reinterpret_cast<float4*>(wts + (size_t)b * NTOK) + tid;
    float4 lg = *wp;
    lg.x = __expf(lg.x - M) * inv;
    lg.y = __expf(lg.y - M) * inv;
    lg.z = __expf(lg.z - M) * inv;
    lg.w = __expf(lg.w - M) * inv;
    *wp = lg;
}

extern "C" void kernel_launch(void* const* d_in, const int* in_sizes, int n_in,
                              void* d_out, int out_size, void* d_ws, size_t ws_size,
                              hipStream_t stream) {
    const float* x     = (const float*)d_in[0];
    const float* gamma = (const float*)d_in[1];
    const float* beta  = (const float*)d_in[2];
    const float* W1    = (const float*)d_in[3];
    const float* b1    = (const float*)d_in[4];
    const float* W2    = (const float*)d_in[5];
    // d_in[6] = b2: softmax-invariant, unused.

    float* out     = (float*)d_out;
    float* summary = out;                       // B*D
    float* wts     = out + (size_t)BDIM * DDIM; // B*N (logits staged, then weights)

    // ws layout: c12 (512B) | ghi (32KB) | glo (32KB) | Sc (16MB) | ml (128KB)
    float*  c12 = (float*)d_ws;
    ushort* ghi = (ushort*)((char*)d_ws + 512);
    ushort* glo = ghi + 16384;
    float*  Sc  = (float*)((char*)d_ws + 512 + 65536);
    float2* ml  = (float2*)((char*)d_ws + 512 + 65536 +
                            (size_t)BDIM * NCH * DDIM * sizeof(float));

    hipLaunchKernelGGL(k_pre, dim3(64), dim3(256), 0, stream,
                       gamma, beta, W1, b1, c12, ghi, glo);
    hipLaunchKernelGGL(k_fused, dim3(BDIM * NTOK / 64), dim3(256), 0, stream,
                       x, c12, ghi, glo, W2, wts, Sc, ml);
    hipLaunchKernelGGL(k_combine, dim3(BDIM), dim3(256), 0, stream,
                       Sc, ml, summary, wts);
}

// Round 18
// 73.536 us; speedup vs baseline: 1.6414x; 1.6414x over previous
//
#include <hip/hip_runtime.h>
#include <math.h>

#define DDIM 256
#define HDIM 64
#define NTOK 1024
#define BDIM 256
#define NCH  16      // chunks per batch (NTOK/64)

typedef __attribute__((ext_vector_type(8))) short short8;
typedef __attribute__((ext_vector_type(4))) float f32x4;

__device__ __forceinline__ ushort f2bf(float f) {   // RNE f32 -> bf16 bits
    uint u = __float_as_uint(f);
    return (ushort)((u + 0x7FFF + ((u >> 16) & 1)) >> 16);
}
__device__ __forceinline__ float bf2f(ushort b) {
    return __uint_as_float(((uint)b) << 16);
}

// Abramowitz-Stegun 7.1.26 erf, |err| <= 1.5e-7.
__device__ __forceinline__ float erf_fast(float x) {
    float ax = fabsf(x);
    float t  = __builtin_amdgcn_rcpf(fmaf(0.3275911f, ax, 1.0f));
    float e  = __expf(-ax * ax);
    float p  = t * fmaf(t, fmaf(t, fmaf(t, fmaf(t, 1.061405429f, -1.453152027f),
                                        1.421413741f), -0.284496736f), 0.254829592f);
    float r  = fmaf(-p, e, 1.0f);
    return copysignf(r, x);
}

// ---------------- k_pre: c12 + bf16-hi pack of G = gamma ⊙ W1 in B-frag order.
// (glo retained in ws layout but no longer consumed by k_fused — R18 drops the
// Ah·bl product; G-residual error ~8e-4 in logits, well under threshold.)
__global__ void k_pre(const float* __restrict__ gamma, const float* __restrict__ beta,
                      const float* __restrict__ W1, const float* __restrict__ b1,
                      float* __restrict__ c12, ushort* __restrict__ ghi,
                      ushort* __restrict__ glo) {
    int tid = threadIdx.x;
    if (blockIdx.x == 0 && tid < HDIM) {
        float s1 = 0.f, s2 = 0.f;
        for (int d = 0; d < DDIM; ++d) {
            float w = W1[d * HDIM + tid];
            s1 = fmaf(gamma[d], w, s1);
            s2 = fmaf(beta[d],  w, s2);
        }
        c12[tid]        = s1;
        c12[HDIM + tid] = s2 + b1[tid];
    }
    int e = blockIdx.x * 256 + tid;            // 64 blocks x 256 = 16384 entries
    int j    = e & 7;
    int lane = (e >> 3) & 63;
    int nt   = (e >> 9) & 3;
    int kt   = e >> 11;
    int k = kt * 32 + (lane >> 4) * 8 + j;
    int n = nt * 16 + (lane & 15);
    float g = gamma[k] * W1[k * HDIM + n];
    ushort hi = f2bf(g);
    ushort lo = f2bf(g - bf2f(hi));
    ghi[e] = hi;
    glo[e] = lo;
}

// ---------------- k_fused (R15 structure; Ah·bl product dropped -> glo plane
// never loaded: G-requests 512->256/wave, MFMA 96->64/wave):
// Phase 1: LN-stats + RNE bf16 hi/lo split of x + 2-product MFMA; hi fragments
// ALSO stored to XOR-swizzled LDS. Phase 2: chunk softmax + weighted sum from LDS.
__global__ __launch_bounds__(256) void k_fused(
    const float* __restrict__ x, const float* __restrict__ c12,
    const ushort* __restrict__ ghi, const ushort* __restrict__ glo,
    const float* __restrict__ W2, float* __restrict__ logits,
    float* __restrict__ Sc, float2* __restrict__ ml) {
    __shared__ ushort Xh[64][256];   // 32KB: bf16-hi of the block's 64x256 tile
    __shared__ float  slog[64];
    __shared__ float4 Sw[4][64];
    __shared__ float  lsum[4];

    int tid = threadIdx.x, w = tid >> 6, lane = tid & 63;
    int m = lane & 15, kg = lane >> 4;
    size_t tok0 = (size_t)blockIdx.x * 64;          // block's 64 tokens
    size_t wtok = tok0 + (size_t)w * 16;            // wave's 16 tokens

    const float4* rp  = reinterpret_cast<const float4*>(x + (wtok + m) * DDIM + kg * 8);
    const short8* gph = reinterpret_cast<const short8*>(ghi);
    char* xh_w = reinterpret_cast<char*>(Xh) + (w * 16 + m) * 512;
    uint  swz  = ((uint)(m & 7)) << 4;

    f32x4 acc[4];
    #pragma unroll
    for (int nt = 0; nt < 4; ++nt) acc[nt] = (f32x4){0.f, 0.f, 0.f, 0.f};

    float s1 = 0.f, s2 = 0.f;

    #pragma unroll
    for (int kt = 0; kt < 8; ++kt) {
        float4 xa = rp[kt * 8];        // k = kt*32 + kg*8 + {0..3}
        float4 xb = rp[kt * 8 + 1];    // k = kt*32 + kg*8 + {4..7}

        s1 += ((xa.x + xa.y) + (xa.z + xa.w)) + ((xb.x + xb.y) + (xb.z + xb.w));
        s2 = fmaf(xa.x, xa.x, s2); s2 = fmaf(xa.y, xa.y, s2);
        s2 = fmaf(xa.z, xa.z, s2); s2 = fmaf(xa.w, xa.w, s2);
        s2 = fmaf(xb.x, xb.x, s2); s2 = fmaf(xb.y, xb.y, s2);
        s2 = fmaf(xb.z, xb.z, s2); s2 = fmaf(xb.w, xb.w, s2);

        uint u0 = __float_as_uint(xa.x), u1 = __float_as_uint(xa.y);
        uint u2 = __float_as_uint(xa.z), u3 = __float_as_uint(xa.w);
        uint u4 = __float_as_uint(xb.x), u5 = __float_as_uint(xb.y);
        uint u6 = __float_as_uint(xb.z), u7 = __float_as_uint(xb.w);

        // RNE hi: t = u + 0x7FFF + round_bit; hi<<16 = t & 0xFFFF0000.
        uint t0 = u0 + 0x7FFFu + ((u0 >> 16) & 1u);
        uint t1 = u1 + 0x7FFFu + ((u1 >> 16) & 1u);
        uint t2 = u2 + 0x7FFFu + ((u2 >> 16) & 1u);
        uint t3 = u3 + 0x7FFFu + ((u3 >> 16) & 1u);
        uint t4 = u4 + 0x7FFFu + ((u4 >> 16) & 1u);
        uint t5 = u5 + 0x7FFFu + ((u5 >> 16) & 1u);
        uint t6 = u6 + 0x7FFFu + ((u6 >> 16) & 1u);
        uint t7 = u7 + 0x7FFFu + ((u7 >> 16) & 1u);

        union { uint4 u; short8 s; } Ah, Al;
        Ah.u.x = (t0 >> 16) | (t1 & 0xFFFF0000u);
        Ah.u.y = (t2 >> 16) | (t3 & 0xFFFF0000u);
        Ah.u.z = (t4 >> 16) | (t5 & 0xFFFF0000u);
        Ah.u.w = (t6 >> 16) | (t7 & 0xFFFF0000u);

        // exact residual vs RNE hi, then RTZ to bf16.
        float l0 = xa.x - __uint_as_float(t0 & 0xFFFF0000u);
        float l1 = xa.y - __uint_as_float(t1 & 0xFFFF0000u);
        float l2 = xa.z - __uint_as_float(t2 & 0xFFFF0000u);
        float l3 = xa.w - __uint_as_float(t3 & 0xFFFF0000u);
        float l4 = xb.x - __uint_as_float(t4 & 0xFFFF0000u);
        float l5 = xb.y - __uint_as_float(t5 & 0xFFFF0000u);
        float l6 = xb.z - __uint_as_float(t6 & 0xFFFF0000u);
        float l7 = xb.w - __uint_as_float(t7 & 0xFFFF0000u);
        Al.u.x = (__float_as_uint(l0) >> 16) | (__float_as_uint(l1) & 0xFFFF0000u);
        Al.u.y = (__float_as_uint(l2) >> 16) | (__float_as_uint(l3) & 0xFFFF0000u);
        Al.u.z = (__float_as_uint(l4) >> 16) | (__float_as_uint(l5) & 0xFFFF0000u);
        Al.u.w = (__float_as_uint(l6) >> 16) | (__float_as_uint(l7) & 0xFFFF0000u);

        // Stash hi tile for phase 2 (swizzled: bijective within each 8-row stripe).
        *reinterpret_cast<uint4*>(xh_w + (((uint)(kt * 64 + kg * 16)) ^ swz)) = Ah.u;

        #pragma unroll
        for (int nt = 0; nt < 4; ++nt) {
            int frag = (kt * 4 + nt) * 64 + lane;
            short8 bh = gph[frag];     // lane-stride 16B: coalesced, 8 lines/instr
            acc[nt] = __builtin_amdgcn_mfma_f32_16x16x32_bf16(Ah.s, bh, acc[nt], 0, 0, 0);
            acc[nt] = __builtin_amdgcn_mfma_f32_16x16x32_bf16(Al.s, bh, acc[nt], 0, 0, 0);
        }
    }

    // Row stats: union over the 4 kg-groups = full row; reduce across kg.
    s1 += __shfl_xor(s1, 16); s1 += __shfl_xor(s1, 32);
    s2 += __shfl_xor(s2, 16); s2 += __shfl_xor(s2, 32);
    float mu  = s1 * (1.f / DDIM);
    float var = fmaf(-mu, mu, s2 * (1.f / DDIM));
    float sv  = rsqrtf(var + 1e-5f);

    // Epilogue: LN fixup + fast-erf GELU + W2 dot; logits -> LDS + global.
    float c1v[4], c2v[4], w2v[4];
    #pragma unroll
    for (int nt = 0; nt < 4; ++nt) {
        c1v[nt] = c12[nt * 16 + m];
        c2v[nt] = c12[HDIM + nt * 16 + m];
        w2v[nt] = W2[nt * 16 + m];
    }
    #pragma unroll
    for (int r = 0; r < 4; ++r) {
        int row = kg * 4 + r;
        float mur = __shfl(mu, row);
        float svr = __shfl(sv, row);
        float v = 0.f;
        #pragma unroll
        for (int nt = 0; nt < 4; ++nt) {
            float pre = fmaf(svr, fmaf(-mur, c1v[nt], acc[nt][r]), c2v[nt]);
            float g   = 0.5f * pre * (1.f + erf_fast(pre * 0.70710678118654752f));
            v = fmaf(g, w2v[nt], v);
        }
        v += __shfl_xor(v, 1); v += __shfl_xor(v, 2);
        v += __shfl_xor(v, 4); v += __shfl_xor(v, 8);
        if (m == 0) {
            slog[w * 16 + row]  = v;
            logits[wtok + row]  = v;
        }
    }
    __syncthreads();

    // ---- Phase 2: chunk softmax + weighted sum from the LDS hi-tile.
    const float4* sl4 = reinterpret_cast<const float4*>(slog);
    float mc = -1e30f;
    #pragma unroll
    for (int i = 0; i < 16; ++i) {
        float4 q = sl4[i];
        mc = fmaxf(mc, fmaxf(fmaxf(q.x, q.y), fmaxf(q.z, q.w)));
    }

    float4 a4 = {0.f, 0.f, 0.f, 0.f};
    float lw = 0.f;
    const char* xh_r = reinterpret_cast<const char*>(Xh);
    uint cb0 = 8u * (uint)lane;                   // lane owns cols 4l..4l+3
    #pragma unroll
    for (int r = 0; r < 16; ++r) {
        int row = w * 16 + r;
        float p = __expf(slog[row] - mc);
        lw += p;
        uint2 hb = *reinterpret_cast<const uint2*>(
            xh_r + row * 512 + (cb0 ^ (((uint)(r & 7)) << 4)));
        a4.x = fmaf(p, __uint_as_float(hb.x << 16),         a4.x);
        a4.y = fmaf(p, __uint_as_float(hb.x & 0xFFFF0000u), a4.y);
        a4.z = fmaf(p, __uint_as_float(hb.y << 16),         a4.z);
        a4.w = fmaf(p, __uint_as_float(hb.y & 0xFFFF0000u), a4.w);
    }
    Sw[w][lane] = a4;
    if (lane == 0) lsum[w] = lw;
    __syncthreads();

    if (w == 0) {
        float4 q0 = Sw[0][lane], q1 = Sw[1][lane], q2 = Sw[2][lane], q3 = Sw[3][lane];
        float4 S;
        S.x = (q0.x + q1.x) + (q2.x + q3.x);
        S.y = (q0.y + q1.y) + (q2.y + q3.y);
        S.z = (q0.z + q1.z) + (q2.z + q3.z);
        S.w = (q0.w + q1.w) + (q2.w + q3.w);
        reinterpret_cast<float4*>(Sc + (size_t)blockIdx.x * DDIM)[lane] = S;
        if (lane == 0)
            ml[blockIdx.x] = make_float2(mc, (lsum[0] + lsum[1]) + (lsum[2] + lsum[3]));
    }
}

// ---------------- k_combine: per batch, merge 16 chunks -> summary + weights.
__global__ __launch_bounds__(256) void k_combine(
    const float* __restrict__ Sc, const float2* __restrict__ ml,
    float* __restrict__ summary, float* __restrict__ wts) {
    int b = blockIdx.x, tid = threadIdx.x;

    float2 mlv[NCH];
    float M = -1e30f;
    #pragma unroll
    for (int c = 0; c < NCH; ++c) { mlv[c] = ml[b * NCH + c]; M = fmaxf(M, mlv[c].x); }
    float ex[NCH];
    float denom = 0.f;
    #pragma unroll
    for (int c = 0; c < NCH; ++c) {
        ex[c] = __expf(mlv[c].x - M);
        denom = fmaf(ex[c], mlv[c].y, denom);
    }
    float inv = 1.f / denom;

    float s = 0.f;
    #pragma unroll
    for (int c = 0; c < NCH; ++c)
        s = fmaf(ex[c], Sc[((size_t)b * NCH + c) * DDIM + tid], s);
    summary[(size_t)b * DDIM + tid] = s * inv;

    // weights: 4 tokens per thread, in-place over staged logits.
    float4* wp = reinterpret_cast<float4*>(wts + (size_t)b * NTOK) + tid;
    float4 lg = *wp;
    lg.x = __expf(lg.x - M) * inv;
    lg.y = __expf(lg.y - M) * inv;
    lg.z = __expf(lg.z - M) * inv;
    lg.w = __expf(lg.w - M) * inv;
    *wp = lg;
}

extern "C" void kernel_launch(void* const* d_in, const int* in_sizes, int n_in,
                              void* d_out, int out_size, void* d_ws, size_t ws_size,
                              hipStream_t stream) {
    const float* x     = (const float*)d_in[0];
    const float* gamma = (const float*)d_in[1];
    const float* beta  = (const float*)d_in[2];
    const float* W1    = (const float*)d_in[3];
    const float* b1    = (const float*)d_in[4];
    const float* W2    = (const float*)d_in[5];
    // d_in[6] = b2: softmax-invariant, unused.

    float* out     = (float*)d_out;
    float* summary = out;                       // B*D
    float* wts     = out + (size_t)BDIM * DDIM; // B*N (logits staged, then weights)

    // ws layout: c12 (512B) | ghi (32KB) | glo (32KB) | Sc (4MB) | ml (32KB)
    float*  c12 = (float*)d_ws;
    ushort* ghi = (ushort*)((char*)d_ws + 512);
    ushort* glo = ghi + 16384;
    float*  Sc  = (float*)((char*)d_ws + 512 + 65536);
    float2* ml  = (float2*)((char*)d_ws + 512 + 65536 +
                            (size_t)BDIM * NCH * DDIM * sizeof(float));

    hipLaunchKernelGGL(k_pre, dim3(64), dim3(256), 0, stream,
                       gamma, beta, W1, b1, c12, ghi, glo);
    hipLaunchKernelGGL(k_fused, dim3(BDIM * NTOK / 64), dim3(256), 0, stream,
                       x, c12, ghi, glo, W2, wts, Sc, ml);
    hipLaunchKernelGGL(k_combine, dim3(BDIM), dim3(256), 0, stream,
                       Sc, ml, summary, wts);
}